// Round 8
// baseline (100.622 us; speedup 1.0000x reference)
//
#include <hip/hip_runtime.h>
#include <hip/hip_bf16.h>

constexpr int T   = 16384;  // tokens
constexpr int HD  = 4096;   // hidden dim
constexpr int E   = 64;     // experts
constexpr int BK  = 64;     // k per chunk
constexpr int NCH = HD / BK;  // 64 chunks
constexpr int BM  = 32;     // rows per block

using short8 = __attribute__((ext_vector_type(8))) short;
using f32x4  = __attribute__((ext_vector_type(4))) float;

#define AS1 __attribute__((address_space(1)))
#define AS3 __attribute__((address_space(3)))

__device__ __forceinline__ unsigned short f2bf(float x) {
  union { float f; unsigned u; } v; v.f = x;
  return (unsigned short)((v.u + 0x7FFFu + ((v.u >> 16) & 1u)) >> 16);
}
__device__ __forceinline__ float bf2f(unsigned short h) {
  union { float f; unsigned u; } v; v.u = ((unsigned)h) << 16;
  return v.f;
}

__device__ __forceinline__ void gload16(const void* g, void* l) {
  __builtin_amdgcn_global_load_lds((const AS1 void*)g, (AS3 void*)l, 16, 0, 0);
}

// ---------------------------------------------------------------------------
// Kernel 0: pack W (fp32 [64][4096]) into a bf16 hi/lo image laid out for
// contiguous per-wave global loads:
//   img[chunk 64][kk 2][part 2][expert 64][q 4] x 8 shorts (16B)
// part 0 = hi bf16 of k-group g = 4*kk+q (8 k's), part 1 = lo residual.
// ---------------------------------------------------------------------------
__global__ __launch_bounds__(256) void wprep(const float* __restrict__ W,
                                             short* __restrict__ img) {
  const int tid  = blockIdx.x * 256 + threadIdx.x;  // 0..65535
  const int c    = tid >> 10;         // chunk
  const int kk   = (tid >> 9) & 1;
  const int part = (tid >> 8) & 1;
  const int e    = (tid >> 2) & 63;
  const int q    = tid & 3;
  const int g    = 4 * kk + q;        // k-group within chunk
  const float* src = W + (size_t)e * HD + c * BK + g * 8;
  short8 v;
#pragma unroll
  for (int j = 0; j < 8; ++j) {
    float x = src[j];
    unsigned short h = f2bf(x);
    v[j] = part ? (short)f2bf(x - bf2f(h)) : (short)h;
  }
  *(short8*)(img + (size_t)tid * 8) = v;
}

// ---------------------------------------------------------------------------
// Kernel 1: logits = H x W^T (split-bf16 MFMA, 3 terms) + fused top-2.
// 512 blocks x 512 threads (8 waves) = 2 blocks/CU, 16 waves/CU.
// A: DMA->LDS, 5 rotating buffers, staged DEPTH-3 (stage t+3 in body t) so
//    the in-order vmcnt wait never touches a load younger than 2 bodies.
// B: global->VGPR depth-1 from the L2-resident image (1-body slack >> L2 lat).
// Body t: loadB(t+1); stageA(t+3); s_waitcnt vmcnt(6); s_barrier; compute(t).
//   vmcnt(6) keeps {A(t+2), B(t+1)x4, A(t+3)} in flight, drains A(t)/B(t).
// ---------------------------------------------------------------------------
__global__ __launch_bounds__(512, 4) void router_gemm(
    const float* __restrict__ H, const short* img,
    float* __restrict__ logits, float* topw, float* topi) {
  // A: 5 x 8 KB @ 0; cand: 2 KB @ 40 KB
  __shared__ __align__(16) char lds[43008];
  char* const ldsA = lds;
  float* const cand = (float*)(lds + 40960);  // [32 rows][4 ct][v1,i1,v2,i2]

  const int tid  = threadIdx.x;
  const int w    = tid >> 6;
  const int lane = tid & 63;
  const int q    = lane >> 4;   // 0..3
  const int r    = lane & 15;   // 0..15
  const int rt   = w >> 2;      // row-tile 0..1
  const int ct   = w & 3;       // col-tile 0..3
  const int row0 = blockIdx.x * BM;

  f32x4 acc = {0.f, 0.f, 0.f, 0.f};

  // --- A staging: 1 DMA inst per wave per chunk (wave-uniform LDS base) ---
  auto stageA = [&](int c, int buf) {
    const int R  = tid >> 4;
    const int sp = tid & 15;
    const int s  = (sp & 8) | ((sp & 7) ^ (R & 7));
    const char* src = (const char*)(H + (size_t)(row0 + R) * HD + c * BK) + s * 16;
    gload16(src, ldsA + buf * 8192 + w * 1024);  // HW adds lane*16
  };

  // --- B register prefetch: 4 x 1KB contiguous loads per wave per chunk ---
  const short* pBe = img + ((size_t)(16 * ct + r) * 4 + q) * 8;
  short8 Bh[2][2], Bl[2][2];   // [parity][kk] — all indices compile-time
  auto loadB = [&](int t, int s) {
#pragma unroll
    for (int kk = 0; kk < 2; ++kk) {
      Bh[s][kk] = *(const short8*)(pBe + (size_t)t * 8192 + kk * 4096);
      Bl[s][kk] = *(const short8*)(pBe + (size_t)t * 8192 + kk * 4096 + 2048);
    }
  };

  const int Arow = 16 * rt + r;
  const int ra   = r & 7;

  // HW packed f32->bf16 split: hi = rne(x,y), lo = rne(residual)
  auto cvtpk = [&](float x, float y, unsigned& hw, unsigned& lw) {
    union { __hip_bfloat162 b; unsigned u; } Hh, Ll;
    Hh.b = __float22bfloat162_rn(float2{x, y});
    float2 hf = __bfloat1622float2(Hh.b);
    Ll.b = __float22bfloat162_rn(float2{x - hf.x, y - hf.y});
    hw = Hh.u; lw = Ll.u;
  };

  auto compute = [&](int abuf, int s) {
    const char* Ab = ldsA + abuf * 8192 + Arow * 256;
#pragma unroll
    for (int kk = 0; kk < 2; ++kk) {
      const int s0  = 8 * kk + 2 * q;
      const int sp0 = (s0 & 8) | ((s0 & 7) ^ ra);
      const int s1  = s0 + 1;
      const int sp1 = (s1 & 8) | ((s1 & 7) ^ ra);
      f32x4 a0 = *(const f32x4*)(Ab + sp0 * 16);
      f32x4 a1 = *(const f32x4*)(Ab + sp1 * 16);
      union { short8 v; unsigned u[4]; } AH, AL;
      cvtpk(a0[0], a0[1], AH.u[0], AL.u[0]);
      cvtpk(a0[2], a0[3], AH.u[1], AL.u[1]);
      cvtpk(a1[0], a1[1], AH.u[2], AL.u[2]);
      cvtpk(a1[2], a1[3], AH.u[3], AL.u[3]);
      acc = __builtin_amdgcn_mfma_f32_16x16x32_bf16(AH.v, Bh[s][kk], acc, 0, 0, 0);
      acc = __builtin_amdgcn_mfma_f32_16x16x32_bf16(AL.v, Bh[s][kk], acc, 0, 0, 0);
      acc = __builtin_amdgcn_mfma_f32_16x16x32_bf16(AH.v, Bl[s][kk], acc, 0, 0, 0);
    }
  };

  // --- prologue: A(0),A(1),B(0),A(2) -> stream: A0 A1 B0x4 A2 ---
  stageA(0, 0);
  stageA(1, 1);
  loadB(0, 0);
  stageA(2, 2);

  int cb = 0;   // LDS buffer of chunk t   (t mod 5)
  int sb = 3;   // LDS buffer for chunk t+3
  // main loop bodies t = 0..59 (unroll x2 for compile-time B parity)
  for (int t = 0; t < NCH - 4; t += 2) {
    {  // even body
      loadB(t + 1, 1);
      stageA(t + 3, sb);
      asm volatile("s_waitcnt vmcnt(6)\n\ts_barrier" ::: "memory");
      compute(cb, 0);
      cb = (cb == 4) ? 0 : cb + 1;
      sb = (sb == 4) ? 0 : sb + 1;
    }
    {  // odd body
      loadB(t + 2, 0);
      stageA(t + 4, sb);
      asm volatile("s_waitcnt vmcnt(6)\n\ts_barrier" ::: "memory");
      compute(cb, 1);
      cb = (cb == 4) ? 0 : cb + 1;
      sb = (sb == 4) ? 0 : sb + 1;
    }
  }
  // t = 60: last A stage (A(63))
  loadB(61, 1);
  stageA(63, sb);
  asm volatile("s_waitcnt vmcnt(6)\n\ts_barrier" ::: "memory");
  compute(cb, 0);
  cb = (cb == 4) ? 0 : cb + 1;
  // t = 61
  loadB(62, 0);
  asm volatile("s_waitcnt vmcnt(5)\n\ts_barrier" ::: "memory");
  compute(cb, 1);
  cb = (cb == 4) ? 0 : cb + 1;
  // t = 62
  loadB(63, 1);
  asm volatile("s_waitcnt vmcnt(4)\n\ts_barrier" ::: "memory");
  compute(cb, 0);
  cb = (cb == 4) ? 0 : cb + 1;
  // t = 63
  asm volatile("s_waitcnt vmcnt(0)\n\ts_barrier" ::: "memory");
  compute(cb, 1);

  // --- epilogue: logits write (D layout: col = lane&15, row = 4q+rr) ---
  const int orow0 = row0 + 16 * rt + 4 * q;
#pragma unroll
  for (int rr = 0; rr < 4; ++rr)
    logits[(size_t)(orow0 + rr) * E + 16 * ct + r] = acc[rr];

  // per-wave top-2 over this wave's 16 experts, for each of its 4 rows
#pragma unroll
  for (int rr = 0; rr < 4; ++rr) {
    const int myi = 16 * ct + r;
    float v1 = acc[rr]; int i1 = myi;
#pragma unroll
    for (int off = 1; off < 16; off <<= 1) {
      float ov = __shfl_xor(v1, off); int oi = __shfl_xor(i1, off);
      if (ov > v1 || (ov == v1 && oi < i1)) { v1 = ov; i1 = oi; }
    }
    float v2 = (myi == i1) ? -3.4e38f : acc[rr]; int i2 = myi;
#pragma unroll
    for (int off = 1; off < 16; off <<= 1) {
      float ov = __shfl_xor(v2, off); int oi = __shfl_xor(i2, off);
      if (ov > v2 || (ov == v2 && oi < i2)) { v2 = ov; i2 = oi; }
    }
    if (r == 0) {
      float* cd = cand + ((size_t)(16 * rt + 4 * q + rr) * 4 + ct) * 4;
      cd[0] = v1; cd[1] = (float)i1; cd[2] = v2; cd[3] = (float)i2;
    }
  }
  __syncthreads();

  // merge 4 col-tile candidate pairs per row; renormalized top-2 weights
  if (tid < BM) {
    const float* cd = cand + (size_t)tid * 16;   // 8 (v,i) pairs
    float bv = -3.4e38f; int bi = 1 << 30;
#pragma unroll
    for (int j = 0; j < 8; ++j) {
      float v = cd[2 * j]; int i = (int)cd[2 * j + 1];
      if (v > bv || (v == bv && i < bi)) { bv = v; bi = i; }
    }
    float sv = -3.4e38f; int si = 1 << 30;
#pragma unroll
    for (int j = 0; j < 8; ++j) {
      float v = cd[2 * j]; int i = (int)cd[2 * j + 1];
      if (i != bi && (v > sv || (v == sv && i < si))) { sv = v; si = i; }
    }
    // w1 = p1/(p1+p2) = 1/(1+e^{x2-x1}); softmax denominator cancels
    const float w1 = 1.0f / (1.0f + __expf(sv - bv));
    const int R = row0 + tid;
    topw[(size_t)R * 2 + 0] = w1;
    topw[(size_t)R * 2 + 1] = 1.0f - w1;
    topi[(size_t)R * 2 + 0] = (float)bi;
    topi[(size_t)R * 2 + 1] = (float)si;
  }
}

extern "C" void kernel_launch(void* const* d_in, const int* in_sizes, int n_in,
                              void* d_out, int out_size, void* d_ws, size_t ws_size,
                              hipStream_t stream) {
  const float* H = (const float*)d_in[0];  // [16384, 4096] fp32
  const float* W = (const float*)d_in[1];  // [64, 4096] fp32

  float* out    = (float*)d_out;
  float* topw   = out;                       // [16384, 2]
  float* logits = out + (size_t)T * 2;       // [16384, 64]
  float* topi   = logits + (size_t)T * E;    // [16384, 2] (indices as float)

  short* wimg = (short*)d_ws;                // 1 MiB packed W image

  wprep<<<256, 256, 0, stream>>>(W, wimg);
  router_gemm<<<T / BM, 512, 0, stream>>>(H, wimg, logits, topw, topi);
}